// Round 3
// baseline (481.583 us; speedup 1.0000x reference)
//
#include <hip/hip_runtime.h>
#include <hip/hip_bf16.h>

// Problem constants (match reference)
#define B_DIM 8192
#define D_DIM 1024
#define N_DIM 4096
#define TAU_INV 5.0f

typedef __bf16 bf16x8 __attribute__((ext_vector_type(8)));
typedef __bf16 bf16x4 __attribute__((ext_vector_type(4)));
typedef float  f32x4  __attribute__((ext_vector_type(4)));

// ---------------------------------------------------------------------------
// async global->LDS, 16B per lane (guide §5: width=16 is the fast path)
__device__ __forceinline__ void gld_lds16(const void* g, void* l) {
  __builtin_amdgcn_global_load_lds((const __attribute__((address_space(1))) void*)g,
                                   (__attribute__((address_space(3))) void*)l,
                                   16, 0, 0);
}

// ---------------------------------------------------------------------------
// prep_x: x (f32 [B,D]) -> xh, xl (bf16 [B,D]), x ~= xh + xl
__global__ void prep_x(const float* __restrict__ x,
                       __bf16* __restrict__ xh, __bf16* __restrict__ xl) {
  const int i = blockIdx.x * blockDim.x + threadIdx.x;   // 2,097,152 threads
  const int base = i * 4;
  const float4 v = *reinterpret_cast<const float4*>(x + base);
  float vv[4] = {v.x, v.y, v.z, v.w};
  bf16x4 h, l;
#pragma unroll
  for (int j = 0; j < 4; ++j) {
    __bf16 hb = (__bf16)vv[j];
    h[j] = hb;
    l[j] = (__bf16)(vv[j] - (float)hb);
  }
  *reinterpret_cast<bf16x4*>(xh + base) = h;
  *reinterpret_cast<bf16x4*>(xl + base) = l;
}

// ---------------------------------------------------------------------------
// prep_w: W (f32 [D,N]) -> wh_t, wl_t (bf16 [N,D]) transposed + split
__global__ void prep_w(const float* __restrict__ W,
                       __bf16* __restrict__ wht, __bf16* __restrict__ wlt) {
  __shared__ float tile[32][33];                 // +1 pad: no bank conflicts
  const int tn = blockIdx.x & 127;               // N/32 = 128 tiles
  const int tk = blockIdx.x >> 7;                // D/32 = 32 tiles
  const int tx = threadIdx.x & 31;
  const int ty = threadIdx.x >> 5;               // 0..7
#pragma unroll
  for (int r = 0; r < 4; ++r) {
    const int k = tk * 32 + ty + r * 8;
    tile[ty + r * 8][tx] = W[(size_t)k * N_DIM + tn * 32 + tx];
  }
  __syncthreads();
#pragma unroll
  for (int r = 0; r < 4; ++r) {
    const int nn = tn * 32 + ty + r * 8;
    const int kk = tk * 32 + tx;
    const float v = tile[tx][ty + r * 8];
    const __bf16 h = (__bf16)v;
    wht[(size_t)nn * D_DIM + kk] = h;
    wlt[(size_t)nn * D_DIM + kk] = (__bf16)(v - (float)h);
  }
}

// ---------------------------------------------------------------------------
// fused GEMM (3-term bf16 split) + bias + segment activation epilogue
// 128x128 tile, BK=32, 4 waves (2x2), 16x16x32 bf16 MFMA, global_load_lds.
#define BM 128
#define BN 128
#define BK 32

__global__ __launch_bounds__(256) void gemm_fused(
    const __bf16* __restrict__ xh, const __bf16* __restrict__ xl,
    const __bf16* __restrict__ wht, const __bf16* __restrict__ wlt,
    const float* __restrict__ bias, const float* __restrict__ gumbel,
    const int* __restrict__ flags, float* __restrict__ out) {
  __shared__ __bf16 As[BM * BK];   // 8 KB, row-major [128][32]
  __shared__ __bf16 Bs[BN * BK];   // 8 KB (Wt rows = C columns)

  const int tid  = threadIdx.x;
  const int lane = tid & 63;
  const int wave = tid >> 6;
  const int wr = wave >> 1;        // wave row (0..1)
  const int wc = wave & 1;         // wave col (0..1)
  const int fr = lane & 15;        // fragment row/col within 16
  const int ko = (lane >> 4) * 8;  // fragment k offset

  const int tm = blockIdx.x & 63;  // M/BM = 64
  const int tn = blockIdx.x >> 6;  // N/BN = 32
  const int row0 = tm * BM;
  const int col0 = tn * BN;

  f32x4 acc[4][4];
#pragma unroll
  for (int m = 0; m < 4; ++m)
#pragma unroll
    for (int n = 0; n < 4; ++n) acc[m][n] = (f32x4){0.f, 0.f, 0.f, 0.f};

  // split product: x*W ~= xh*wh + xh*wl + xl*wh
  const __bf16* Aparts[3] = {xh, xh, xl};
  const __bf16* Bparts[3] = {wht, wlt, wht};

  for (int p = 0; p < 3; ++p) {
    const __bf16* Ab = Aparts[p] + (size_t)row0 * D_DIM;
    const __bf16* Bb = Bparts[p] + (size_t)col0 * D_DIM;
    for (int kk = 0; kk < D_DIM; kk += BK) {
      // stage A and B tiles: 512 chunks x 16B each, lane-linear LDS dest
#pragma unroll
      for (int i = 0; i < 2; ++i) {
        const int c = wave * 64 + lane + i * 256;  // chunk id 0..511
        const int r = c >> 2;                      // tile row 0..127
        const int s = c & 3;                       // 16B chunk within 64B row
        gld_lds16(Ab + (size_t)r * D_DIM + kk + s * 8, As + c * 8);
        gld_lds16(Bb + (size_t)r * D_DIM + kk + s * 8, Bs + c * 8);
      }
      __syncthreads();  // compiler emits vmcnt(0) drain before barrier

      bf16x8 a[4], b[4];
#pragma unroll
      for (int m = 0; m < 4; ++m)
        a[m] = *reinterpret_cast<const bf16x8*>(&As[(wr * 64 + m * 16 + fr) * BK + ko]);
#pragma unroll
      for (int n = 0; n < 4; ++n)
        b[n] = *reinterpret_cast<const bf16x8*>(&Bs[(wc * 64 + n * 16 + fr) * BK + ko]);
#pragma unroll
      for (int m = 0; m < 4; ++m)
#pragma unroll
        for (int n = 0; n < 4; ++n)
          acc[m][n] = __builtin_amdgcn_mfma_f32_16x16x32_bf16(a[m], b[n], acc[m][n], 0, 0, 0);
      __syncthreads();
    }
  }

  // ---- epilogue: bias, out0 store, segment activation, out1 store ----
  const int grow0 = row0 + wr * 64;
  const int gcol0 = col0 + wc * 64;
  float* out0 = out;
  float* out1 = out + (size_t)B_DIM * N_DIM;

#pragma unroll
  for (int n = 0; n < 4; ++n) {
    const int col = gcol0 + n * 16 + fr;
    const int seg = col >> 4;            // uniform across the wave
    const int flag = flags[seg];
    const float bv = bias[col];
#pragma unroll
    for (int m = 0; m < 4; ++m) {
#pragma unroll
      for (int j = 0; j < 4; ++j) {
        const int row = grow0 + m * 16 + (lane >> 4) * 4 + j;
        const size_t idx = (size_t)row * N_DIM + col;
        const float o = acc[m][n][j] + bv;
        out0[idx] = o;
        float v;
        if (flag == 0) {
          // tanh via exp2-backed __expf; clamp to avoid inf/inf
          const float oc = fminf(fmaxf(o, -15.f), 15.f);
          const float e2 = __expf(2.f * oc);
          v = (e2 - 1.f) / (e2 + 1.f);
        } else {
          // softmax over the 16-wide segment == lanes fr=0..15 of this group
          const float t = (o + gumbel[idx]) * TAU_INV;
          float mx = t;
          mx = fmaxf(mx, __shfl_xor(mx, 1));
          mx = fmaxf(mx, __shfl_xor(mx, 2));
          mx = fmaxf(mx, __shfl_xor(mx, 4));
          mx = fmaxf(mx, __shfl_xor(mx, 8));
          float e = __expf(t - mx);
          float ssum = e;
          ssum += __shfl_xor(ssum, 1);
          ssum += __shfl_xor(ssum, 2);
          ssum += __shfl_xor(ssum, 4);
          ssum += __shfl_xor(ssum, 8);
          v = e / ssum;
        }
        out1[idx] = v;
      }
    }
  }
}

// ---------------------------------------------------------------------------
// fallback (only if ws_size < 48 MB): naive but correct
__global__ void fallback_kernel(const float* __restrict__ x, const float* __restrict__ W,
                                const float* __restrict__ bias, const float* __restrict__ gumbel,
                                const int* __restrict__ flags, float* __restrict__ out) {
  const size_t idx = (size_t)blockIdx.x * blockDim.x + threadIdx.x;
  const int row = (int)(idx / N_DIM);
  const int col = (int)(idx % N_DIM);
  float o = bias[col];
  const float* xr = x + (size_t)row * D_DIM;
  for (int k = 0; k < D_DIM; ++k) o += xr[k] * W[(size_t)k * N_DIM + col];
  out[idx] = o;
  float v;
  if (flags[col >> 4] == 0) {
    const float oc = fminf(fmaxf(o, -15.f), 15.f);
    const float e2 = __expf(2.f * oc);
    v = (e2 - 1.f) / (e2 + 1.f);
  } else {
    const float t = (o + gumbel[idx]) * TAU_INV;
    float mx = t;
    mx = fmaxf(mx, __shfl_xor(mx, 1));
    mx = fmaxf(mx, __shfl_xor(mx, 2));
    mx = fmaxf(mx, __shfl_xor(mx, 4));
    mx = fmaxf(mx, __shfl_xor(mx, 8));
    float e = __expf(t - mx);
    float ssum = e;
    ssum += __shfl_xor(ssum, 1);
    ssum += __shfl_xor(ssum, 2);
    ssum += __shfl_xor(ssum, 4);
    ssum += __shfl_xor(ssum, 8);
    v = e / ssum;
  }
  out[(size_t)B_DIM * N_DIM + idx] = v;
}

// ---------------------------------------------------------------------------
extern "C" void kernel_launch(void* const* d_in, const int* in_sizes, int n_in,
                              void* d_out, int out_size, void* d_ws, size_t ws_size,
                              hipStream_t stream) {
  const float* x      = (const float*)d_in[0];
  const float* W      = (const float*)d_in[1];
  const float* bias   = (const float*)d_in[2];
  const float* gumbel = (const float*)d_in[3];
  const int*   flags  = (const int*)d_in[4];
  float* out = (float*)d_out;

  const size_t xcnt = (size_t)B_DIM * D_DIM;   // 8,388,608
  const size_t wcnt = (size_t)N_DIM * D_DIM;   // 4,194,304
  const size_t need = (2 * xcnt + 2 * wcnt) * sizeof(__bf16);  // 48 MB

  if (ws_size < need) {
    const long long nblocks = (long long)B_DIM * N_DIM / 256;  // 131072
    fallback_kernel<<<(int)nblocks, 256, 0, stream>>>(x, W, bias, gumbel, flags, out);
    return;
  }

  __bf16* xh  = (__bf16*)d_ws;
  __bf16* xl  = xh + xcnt;
  __bf16* wht = xl + xcnt;
  __bf16* wlt = wht + wcnt;

  prep_x<<<xcnt / 4 / 256, 256, 0, stream>>>(x, xh, xl);
  prep_w<<<(N_DIM / 32) * (D_DIM / 32), 256, 0, stream>>>(W, wht, wlt);
  gemm_fused<<<(B_DIM / BM) * (N_DIM / BN), 256, 0, stream>>>(
      xh, xl, wht, wlt, bias, gumbel, flags, out);
}

// Round 4
// 275.313 us; speedup vs baseline: 1.7492x; 1.7492x over previous
//
#include <hip/hip_runtime.h>
#include <hip/hip_bf16.h>

// Problem constants (match reference)
#define B_DIM 8192
#define D_DIM 1024
#define N_DIM 4096
#define TAU_INV 5.0f

typedef __bf16 bf16x8 __attribute__((ext_vector_type(8)));
typedef __bf16 bf16x4 __attribute__((ext_vector_type(4)));
typedef float  f32x4  __attribute__((ext_vector_type(4)));

// ---------------------------------------------------------------------------
// async global->LDS, 16B per lane
__device__ __forceinline__ void gld_lds16(const void* g, void* l) {
  __builtin_amdgcn_global_load_lds((const __attribute__((address_space(1))) void*)g,
                                   (__attribute__((address_space(3))) void*)l,
                                   16, 0, 0);
}

__device__ __forceinline__ float fast_rcp(float x) {
  return __builtin_amdgcn_rcpf(x);
}

// ---------------------------------------------------------------------------
// prep_x: x (f32 [B,D]) -> xh, xl (bf16 [B,D]), x == xh + xl (to bf16 prec^2)
__global__ void prep_x(const float* __restrict__ x,
                       __bf16* __restrict__ xh, __bf16* __restrict__ xl) {
  const int i = blockIdx.x * blockDim.x + threadIdx.x;
  const int base = i * 4;
  const float4 v = *reinterpret_cast<const float4*>(x + base);
  float vv[4] = {v.x, v.y, v.z, v.w};
  bf16x4 h, l;
#pragma unroll
  for (int j = 0; j < 4; ++j) {
    __bf16 hb = (__bf16)vv[j];
    h[j] = hb;
    l[j] = (__bf16)(vv[j] - (float)hb);
  }
  *reinterpret_cast<bf16x4*>(xh + base) = h;
  *reinterpret_cast<bf16x4*>(xl + base) = l;
}

// ---------------------------------------------------------------------------
// prep_w: W (f32 [D,N]) -> wht (bf16 [N,D]) transposed (high part only;
// 2-term split x@wh = xh@wh + xl@wh is exact in x, residual x@wl ~ 7e-3 max)
__global__ void prep_w(const float* __restrict__ W, __bf16* __restrict__ wht) {
  __shared__ float tile[32][33];                 // +1 pad: no bank conflicts
  const int tn = blockIdx.x & 127;               // N/32 = 128 tiles
  const int tk = blockIdx.x >> 7;                // D/32 = 32 tiles
  const int tx = threadIdx.x & 31;
  const int ty = threadIdx.x >> 5;               // 0..7
#pragma unroll
  for (int r = 0; r < 4; ++r) {
    const int k = tk * 32 + ty + r * 8;
    tile[ty + r * 8][tx] = W[(size_t)k * N_DIM + tn * 32 + tx];
  }
  __syncthreads();
#pragma unroll
  for (int r = 0; r < 4; ++r) {
    const int nn = tn * 32 + ty + r * 8;
    const int kk = tk * 32 + tx;
    wht[(size_t)nn * D_DIM + kk] = (__bf16)tile[tx][ty + r * 8];
  }
}

// ---------------------------------------------------------------------------
// fused GEMM (2-term bf16 split, shared B) + bias + segment activations.
// 256x256 tile, BK=32, 8 waves (2x4), swapped-operand 16x16x32 bf16 MFMA:
//   mfma(w_frag, x_frag, acc) => lane holds 4 CONSECUTIVE output columns
//   (row = lane&15, cols = (lane>>4)*4 + reg) -> float4 stores/loads, and
//   the 16-wide segment softmax is in-lane(4) + shfl_xor(16,32).
#define BM 256
#define BN 256
#define BK 32
#define THREADS 512

__global__ __launch_bounds__(THREADS, 2) void gemm_fused(
    const __bf16* __restrict__ xh, const __bf16* __restrict__ xl,
    const __bf16* __restrict__ wht,
    const float* __restrict__ bias, const float* __restrict__ gumbel,
    const int* __restrict__ flags, float* __restrict__ out) {
  __shared__ __bf16 Ash[BM * BK];  // 16 KB  (xh tile)
  __shared__ __bf16 Asl[BM * BK];  // 16 KB  (xl tile)
  __shared__ __bf16 Bs[BN * BK];   // 16 KB  (wht tile; B rows = output cols)

  const int tid  = threadIdx.x;
  const int lane = tid & 63;
  const int wave = tid >> 6;       // 0..7
  const int wr   = wave >> 2;      // 0..1  (M direction, 128 rows each)
  const int wc   = wave & 3;       // 0..3  (N direction, 64 cols each)
  const int fr   = lane & 15;
  const int q4   = lane >> 4;      // 0..3
  const int ko   = q4 * 8;

  // XCD-aware bijective swizzle (512 blocks, 8 XCDs, 64 blocks each):
  // each XCD owns 2 column-panels -> B panel L2-resident.
  const int swz  = (blockIdx.x & 7) * 64 + (blockIdx.x >> 3);
  const int tm   = swz & 31;       // 32 M tiles
  const int tn   = swz >> 5;       // 16 N tiles
  const int row0 = tm * BM;
  const int col0 = tn * BN;

  f32x4 acc[8][4];
#pragma unroll
  for (int m = 0; m < 8; ++m)
#pragma unroll
    for (int n = 0; n < 4; ++n) acc[m][n] = (f32x4){0.f, 0.f, 0.f, 0.f};

  const __bf16* Ah = xh  + (size_t)row0 * D_DIM;
  const __bf16* Al = xl  + (size_t)row0 * D_DIM;
  const __bf16* Bb = wht + (size_t)col0 * D_DIM;

  for (int kk = 0; kk < D_DIM; kk += BK) {
    // stage 3 tiles of 256x32 bf16 = 48 KB: 1024 16B-chunks each,
    // 512 threads x 2 rounds; LDS dest is wave-uniform base + lane*16 (linear)
#pragma unroll
    for (int i = 0; i < 2; ++i) {
      const int c = i * THREADS + tid;       // chunk 0..1023
      const int r = c >> 2;                  // tile row
      const int s = c & 3;                   // 16B chunk in 64B row
      const size_t off = (size_t)r * D_DIM + kk + s * 8;
      gld_lds16(Ah + off, Ash + c * 8);
      gld_lds16(Al + off, Asl + c * 8);
      gld_lds16(Bb + off, Bs  + c * 8);
    }
    __syncthreads();

    bf16x8 b[4];
#pragma unroll
    for (int n = 0; n < 4; ++n)
      b[n] = *reinterpret_cast<const bf16x8*>(&Bs[(wc * 64 + n * 16 + fr) * BK + ko]);
#pragma unroll
    for (int m = 0; m < 8; ++m) {
      const bf16x8 a = *reinterpret_cast<const bf16x8*>(&Ash[(wr * 128 + m * 16 + fr) * BK + ko]);
#pragma unroll
      for (int n = 0; n < 4; ++n)
        acc[m][n] = __builtin_amdgcn_mfma_f32_16x16x32_bf16(b[n], a, acc[m][n], 0, 0, 0);
    }
#pragma unroll
    for (int m = 0; m < 8; ++m) {
      const bf16x8 a = *reinterpret_cast<const bf16x8*>(&Asl[(wr * 128 + m * 16 + fr) * BK + ko]);
#pragma unroll
      for (int n = 0; n < 4; ++n)
        acc[m][n] = __builtin_amdgcn_mfma_f32_16x16x32_bf16(b[n], a, acc[m][n], 0, 0, 0);
    }
    __syncthreads();
  }

  // ---- epilogue ----
  // lane L, frag (m,n), reg j -> out[grow0 + m*16 + (L&15)][gcol0 + n*16 + (L>>4)*4 + j]
  const int grow0 = row0 + wr * 128;
  const int gcol0 = col0 + wc * 64;
  float* out0 = out;
  float* out1 = out + (size_t)B_DIM * N_DIM;

#pragma unroll
  for (int n = 0; n < 4; ++n) {
    const int cb = gcol0 + n * 16 + q4 * 4;
    const float4 bv = *reinterpret_cast<const float4*>(bias + cb);
    const int flag = flags[(gcol0 >> 4) + n];   // one 16-wide segment per frag col
#pragma unroll
    for (int m = 0; m < 8; ++m) {
      const int row = grow0 + m * 16 + fr;
      const size_t idx = (size_t)row * N_DIM + cb;
      const float o0 = acc[m][n][0] + bv.x;
      const float o1 = acc[m][n][1] + bv.y;
      const float o2 = acc[m][n][2] + bv.z;
      const float o3 = acc[m][n][3] + bv.w;
      *reinterpret_cast<float4*>(out0 + idx) = make_float4(o0, o1, o2, o3);

      float4 v;
      if (flag == 0) {
        // tanh
        const float c0 = fminf(fmaxf(o0, -15.f), 15.f);
        const float c1 = fminf(fmaxf(o1, -15.f), 15.f);
        const float c2 = fminf(fmaxf(o2, -15.f), 15.f);
        const float c3 = fminf(fmaxf(o3, -15.f), 15.f);
        const float e0 = __expf(2.f * c0), e1 = __expf(2.f * c1);
        const float e2 = __expf(2.f * c2), e3 = __expf(2.f * c3);
        v.x = (e0 - 1.f) * fast_rcp(e0 + 1.f);
        v.y = (e1 - 1.f) * fast_rcp(e1 + 1.f);
        v.z = (e2 - 1.f) * fast_rcp(e2 + 1.f);
        v.w = (e3 - 1.f) * fast_rcp(e3 + 1.f);
      } else {
        // softmax over 16-wide segment: lane group {L, L^16, L^32, L^48}
        const float4 g = *reinterpret_cast<const float4*>(gumbel + idx);
        const float t0 = (o0 + g.x) * TAU_INV;
        const float t1 = (o1 + g.y) * TAU_INV;
        const float t2 = (o2 + g.z) * TAU_INV;
        const float t3 = (o3 + g.w) * TAU_INV;
        float mx = fmaxf(fmaxf(t0, t1), fmaxf(t2, t3));
        mx = fmaxf(mx, __shfl_xor(mx, 16));
        mx = fmaxf(mx, __shfl_xor(mx, 32));
        const float e0 = __expf(t0 - mx), e1 = __expf(t1 - mx);
        const float e2 = __expf(t2 - mx), e3 = __expf(t3 - mx);
        float s = (e0 + e1) + (e2 + e3);
        s += __shfl_xor(s, 16);
        s += __shfl_xor(s, 32);
        const float inv = fast_rcp(s);
        v.x = e0 * inv; v.y = e1 * inv; v.z = e2 * inv; v.w = e3 * inv;
      }
      *reinterpret_cast<float4*>(out1 + idx) = v;
    }
  }
}

// ---------------------------------------------------------------------------
// fallback (only if ws_size too small): naive but correct
__global__ void fallback_kernel(const float* __restrict__ x, const float* __restrict__ W,
                                const float* __restrict__ bias, const float* __restrict__ gumbel,
                                const int* __restrict__ flags, float* __restrict__ out) {
  const size_t idx = (size_t)blockIdx.x * blockDim.x + threadIdx.x;
  const int row = (int)(idx / N_DIM);
  const int col = (int)(idx % N_DIM);
  float o = bias[col];
  const float* xr = x + (size_t)row * D_DIM;
  for (int k = 0; k < D_DIM; ++k) o += xr[k] * W[(size_t)k * N_DIM + col];
  out[idx] = o;
  float v;
  if (flags[col >> 4] == 0) {
    const float oc = fminf(fmaxf(o, -15.f), 15.f);
    const float e2 = __expf(2.f * oc);
    v = (e2 - 1.f) / (e2 + 1.f);
  } else {
    const float t = (o + gumbel[idx]) * TAU_INV;
    float mx = t;
    mx = fmaxf(mx, __shfl_xor(mx, 1));
    mx = fmaxf(mx, __shfl_xor(mx, 2));
    mx = fmaxf(mx, __shfl_xor(mx, 4));
    mx = fmaxf(mx, __shfl_xor(mx, 8));
    float e = __expf(t - mx);
    float ssum = e;
    ssum += __shfl_xor(ssum, 1);
    ssum += __shfl_xor(ssum, 2);
    ssum += __shfl_xor(ssum, 4);
    ssum += __shfl_xor(ssum, 8);
    v = e / ssum;
  }
  out[(size_t)B_DIM * N_DIM + idx] = v;
}

// ---------------------------------------------------------------------------
extern "C" void kernel_launch(void* const* d_in, const int* in_sizes, int n_in,
                              void* d_out, int out_size, void* d_ws, size_t ws_size,
                              hipStream_t stream) {
  const float* x      = (const float*)d_in[0];
  const float* W      = (const float*)d_in[1];
  const float* bias   = (const float*)d_in[2];
  const float* gumbel = (const float*)d_in[3];
  const int*   flags  = (const int*)d_in[4];
  float* out = (float*)d_out;

  const size_t xcnt = (size_t)B_DIM * D_DIM;   // 8,388,608
  const size_t wcnt = (size_t)N_DIM * D_DIM;   // 4,194,304
  const size_t need = (2 * xcnt + wcnt) * sizeof(__bf16);  // ~42 MB

  if (ws_size < need) {
    const long long nblocks = (long long)B_DIM * N_DIM / 256;  // 131072
    fallback_kernel<<<(int)nblocks, 256, 0, stream>>>(x, W, bias, gumbel, flags, out);
    return;
  }

  __bf16* xh  = (__bf16*)d_ws;
  __bf16* xl  = xh + xcnt;
  __bf16* wht = xl + xcnt;

  prep_x<<<xcnt / 4 / 256, 256, 0, stream>>>(x, xh, xl);
  prep_w<<<(N_DIM / 32) * (D_DIM / 32), 256, 0, stream>>>(W, wht);
  gemm_fused<<<(B_DIM / BM) * (N_DIM / BN), THREADS, 0, stream>>>(
      xh, xl, wht, bias, gumbel, flags, out);
}

// Round 5
// 248.522 us; speedup vs baseline: 1.9378x; 1.1078x over previous
//
#include <hip/hip_runtime.h>
#include <hip/hip_bf16.h>

// Problem constants (match reference)
#define B_DIM 8192
#define D_DIM 1024
#define N_DIM 4096
#define TAU_INV 5.0f

typedef __bf16 bf16x8 __attribute__((ext_vector_type(8)));
typedef __bf16 bf16x4 __attribute__((ext_vector_type(4)));
typedef float  f32x4  __attribute__((ext_vector_type(4)));

// ---------------------------------------------------------------------------
// async global->LDS, 16B per lane
__device__ __forceinline__ void gld_lds16(const void* g, void* l) {
  __builtin_amdgcn_global_load_lds((const __attribute__((address_space(1))) void*)g,
                                   (__attribute__((address_space(3))) void*)l,
                                   16, 0, 0);
}

__device__ __forceinline__ float fast_rcp(float x) {
  return __builtin_amdgcn_rcpf(x);
}

// ---------------------------------------------------------------------------
// prep_x: x (f32 [B,D]) -> xh, xl (bf16 [B,D]), x == xh + xl (to bf16 prec^2)
__global__ void prep_x(const float* __restrict__ x,
                       __bf16* __restrict__ xh, __bf16* __restrict__ xl) {
  const int i = blockIdx.x * blockDim.x + threadIdx.x;
  const int base = i * 4;
  const float4 v = *reinterpret_cast<const float4*>(x + base);
  float vv[4] = {v.x, v.y, v.z, v.w};
  bf16x4 h, l;
#pragma unroll
  for (int j = 0; j < 4; ++j) {
    __bf16 hb = (__bf16)vv[j];
    h[j] = hb;
    l[j] = (__bf16)(vv[j] - (float)hb);
  }
  *reinterpret_cast<bf16x4*>(xh + base) = h;
  *reinterpret_cast<bf16x4*>(xl + base) = l;
}

// ---------------------------------------------------------------------------
// prep_w: W (f32 [D,N]) -> wht (bf16 [N,D]) transposed (high part only;
// 2-term split x@wh = xh@wh + xl@wh is exact in x, residual x@wl ~ 7e-3 max)
__global__ void prep_w(const float* __restrict__ W, __bf16* __restrict__ wht) {
  __shared__ float tile[32][33];                 // +1 pad: no bank conflicts
  const int tn = blockIdx.x & 127;               // N/32 = 128 tiles
  const int tk = blockIdx.x >> 7;                // D/32 = 32 tiles
  const int tx = threadIdx.x & 31;
  const int ty = threadIdx.x >> 5;               // 0..7
#pragma unroll
  for (int r = 0; r < 4; ++r) {
    const int k = tk * 32 + ty + r * 8;
    tile[ty + r * 8][tx] = W[(size_t)k * N_DIM + tn * 32 + tx];
  }
  __syncthreads();
#pragma unroll
  for (int r = 0; r < 4; ++r) {
    const int nn = tn * 32 + ty + r * 8;
    const int kk = tk * 32 + tx;
    wht[(size_t)nn * D_DIM + kk] = (__bf16)tile[tx][ty + r * 8];
  }
}

// ---------------------------------------------------------------------------
// fused GEMM (2-term bf16 split, shared B) + bias + segment activations.
// 256x256 tile, BK=32, 8 waves (2x4), swapped-operand 16x16x32 bf16 MFMA.
// Pipeline: LDS double-buffer + counted vmcnt(6) (stage t+1 issued before
// computing t; never drain to 0 in the loop) + slot-rotation LDS swizzle
// (physical 16B slot = (logical + (row>>1)) & 3; inverse rotation applied to
// the GLOBAL source address so gld_lds dest stays lane-linear) + setprio.
#define BM 256
#define BN 256
#define BK 32
#define THREADS 512
#define NSTEP (D_DIM / BK)   // 32

__global__ __launch_bounds__(THREADS, 2) void gemm_fused(
    const __bf16* __restrict__ xh, const __bf16* __restrict__ xl,
    const __bf16* __restrict__ wht,
    const float* __restrict__ bias, const float* __restrict__ gumbel,
    const int* __restrict__ flags, float* __restrict__ out) {
  __shared__ __align__(16) __bf16 AsH[2][BM * BK];  // 2 x 16 KB (xh tile)
  __shared__ __align__(16) __bf16 AsL[2][BM * BK];  // 2 x 16 KB (xl tile)
  __shared__ __align__(16) __bf16 Bsh[2][BN * BK];  // 2 x 16 KB (wht tile)

  const int tid  = threadIdx.x;
  const int lane = tid & 63;
  const int wave = tid >> 6;       // 0..7
  const int wr   = wave >> 2;      // 0..1  (M direction, 128 rows each)
  const int wc   = wave & 3;       // 0..3  (N direction, 64 cols each)
  const int fr   = lane & 15;
  const int q4   = lane >> 4;      // 0..3
  // swizzled read slot: rotation by (row>>1)&3 == (fr>>1)&3 (row%16 == fr)
  const int prot8 = (((q4 + ((fr >> 1) & 3)) & 3) * 8);

  // XCD-aware swizzle: each XCD owns 4 contiguous row-panels x all 16
  // col-panels -> A panels (4 MB) are L2-resident per XCD, A fetched once.
  const int bx  = blockIdx.x;
  const int xcd = bx & 7;
  const int ii  = bx >> 3;         // 0..63
  const int tm  = xcd * 4 + (ii & 3);  // 0..31
  const int tn  = ii >> 2;             // 0..15
  const int row0 = tm * BM;
  const int col0 = tn * BN;

  f32x4 acc[8][4];
#pragma unroll
  for (int m = 0; m < 8; ++m)
#pragma unroll
    for (int n = 0; n < 4; ++n) acc[m][n] = (f32x4){0.f, 0.f, 0.f, 0.f};

  const __bf16* Ah = xh  + (size_t)row0 * D_DIM;
  const __bf16* Al = xl  + (size_t)row0 * D_DIM;
  const __bf16* Bb = wht + (size_t)col0 * D_DIM;

  // Stage one K-tile (48 KB = 3 x 1024 chunks of 16B) into buffer h.
  // Chunk c -> row r = c>>2, physical slot p = c&3; fetch logical slot
  // l = (p - (r>>1)) & 3 so that reads with +rotation find their data.
#define STAGE(h, kk)                                                        \
  {                                                                         \
    _Pragma("unroll")                                                       \
    for (int i_ = 0; i_ < 2; ++i_) {                                        \
      const int c_ = i_ * THREADS + tid;                                    \
      const int r_ = c_ >> 2;                                               \
      const int l_ = ((c_ & 3) - (r_ >> 1)) & 3;                            \
      const size_t off_ = (size_t)r_ * D_DIM + (kk) + l_ * 8;               \
      gld_lds16(Ah + off_, &AsH[h][c_ * 8]);                                \
      gld_lds16(Al + off_, &AsL[h][c_ * 8]);                                \
      gld_lds16(Bb + off_, &Bsh[h][c_ * 8]);                                \
    }                                                                       \
  }

#define COMPUTE(h)                                                          \
  {                                                                         \
    bf16x8 bfr_[4];                                                         \
    _Pragma("unroll")                                                       \
    for (int n = 0; n < 4; ++n)                                             \
      bfr_[n] = *reinterpret_cast<const bf16x8*>(                           \
          &Bsh[h][(wc * 64 + n * 16 + fr) * BK + prot8]);                   \
    __builtin_amdgcn_s_setprio(1);                                          \
    _Pragma("unroll")                                                       \
    for (int m = 0; m < 8; ++m) {                                           \
      const int ra_ = (wr * 128 + m * 16 + fr) * BK + prot8;                \
      const bf16x8 a0_ = *reinterpret_cast<const bf16x8*>(&AsH[h][ra_]);    \
      _Pragma("unroll")                                                     \
      for (int n = 0; n < 4; ++n)                                           \
        acc[m][n] = __builtin_amdgcn_mfma_f32_16x16x32_bf16(                \
            bfr_[n], a0_, acc[m][n], 0, 0, 0);                              \
      const bf16x8 a1_ = *reinterpret_cast<const bf16x8*>(&AsL[h][ra_]);    \
      _Pragma("unroll")                                                     \
      for (int n = 0; n < 4; ++n)                                           \
        acc[m][n] = __builtin_amdgcn_mfma_f32_16x16x32_bf16(                \
            bfr_[n], a1_, acc[m][n], 0, 0, 0);                              \
    }                                                                       \
    __builtin_amdgcn_s_setprio(0);                                          \
  }

#define WAIT6_BAR                                                           \
  asm volatile("s_waitcnt vmcnt(6)" ::: "memory");                          \
  __builtin_amdgcn_s_barrier();                                             \
  asm volatile("" ::: "memory");

#define END_BAR                                                             \
  __builtin_amdgcn_s_barrier();                                             \
  asm volatile("" ::: "memory");

  STAGE(0, 0)
#pragma unroll 1
  for (int t = 0; t < NSTEP - 2; t += 2) {
    STAGE(1, (t + 1) * BK)
    WAIT6_BAR
    COMPUTE(0)
    END_BAR
    STAGE(0, (t + 2) * BK)
    WAIT6_BAR
    COMPUTE(1)
    END_BAR
  }
  // t = NSTEP-2: stage last tile (31) into buf1, compute tile 30 from buf0
  STAGE(1, (NSTEP - 1) * BK)
  WAIT6_BAR
  COMPUTE(0)
  END_BAR
  asm volatile("s_waitcnt vmcnt(0)" ::: "memory");
  __builtin_amdgcn_s_barrier();
  asm volatile("" ::: "memory");
  COMPUTE(1)

  // ---- epilogue ----
  // lane L, frag (m,n), reg j -> out[grow0 + m*16 + (L&15)][gcol0 + n*16 + (L>>4)*4 + j]
  const int grow0 = row0 + wr * 128;
  const int gcol0 = col0 + wc * 64;
  float* out0 = out;
  float* out1 = out + (size_t)B_DIM * N_DIM;

#pragma unroll
  for (int n = 0; n < 4; ++n) {
    const int cb = gcol0 + n * 16 + q4 * 4;
    const float4 bv = *reinterpret_cast<const float4*>(bias + cb);
    const int flag = flags[(gcol0 >> 4) + n];   // one 16-wide segment per frag col
#pragma unroll
    for (int m = 0; m < 8; ++m) {
      const int row = grow0 + m * 16 + fr;
      const size_t idx = (size_t)row * N_DIM + cb;
      const float o0 = acc[m][n][0] + bv.x;
      const float o1 = acc[m][n][1] + bv.y;
      const float o2 = acc[m][n][2] + bv.z;
      const float o3 = acc[m][n][3] + bv.w;
      *reinterpret_cast<float4*>(out0 + idx) = make_float4(o0, o1, o2, o3);

      float4 v;
      if (flag == 0) {
        // tanh
        const float c0 = fminf(fmaxf(o0, -15.f), 15.f);
        const float c1 = fminf(fmaxf(o1, -15.f), 15.f);
        const float c2 = fminf(fmaxf(o2, -15.f), 15.f);
        const float c3 = fminf(fmaxf(o3, -15.f), 15.f);
        const float e0 = __expf(2.f * c0), e1 = __expf(2.f * c1);
        const float e2 = __expf(2.f * c2), e3 = __expf(2.f * c3);
        v.x = (e0 - 1.f) * fast_rcp(e0 + 1.f);
        v.y = (e1 - 1.f) * fast_rcp(e1 + 1.f);
        v.z = (e2 - 1.f) * fast_rcp(e2 + 1.f);
        v.w = (e3 - 1.f) * fast_rcp(e3 + 1.f);
      } else {
        // softmax over 16-wide segment: lane group {L, L^16, L^32, L^48}
        const float4 g = *reinterpret_cast<const float4*>(gumbel + idx);
        const float t0 = (o0 + g.x) * TAU_INV;
        const float t1 = (o1 + g.y) * TAU_INV;
        const float t2 = (o2 + g.z) * TAU_INV;
        const float t3 = (o3 + g.w) * TAU_INV;
        float mx = fmaxf(fmaxf(t0, t1), fmaxf(t2, t3));
        mx = fmaxf(mx, __shfl_xor(mx, 16));
        mx = fmaxf(mx, __shfl_xor(mx, 32));
        const float e0 = __expf(t0 - mx), e1 = __expf(t1 - mx);
        const float e2 = __expf(t2 - mx), e3 = __expf(t3 - mx);
        float s = (e0 + e1) + (e2 + e3);
        s += __shfl_xor(s, 16);
        s += __shfl_xor(s, 32);
        const float inv = fast_rcp(s);
        v.x = e0 * inv; v.y = e1 * inv; v.z = e2 * inv; v.w = e3 * inv;
      }
      *reinterpret_cast<float4*>(out1 + idx) = v;
    }
  }
}

// ---------------------------------------------------------------------------
// fallback (only if ws_size too small): naive but correct
__global__ void fallback_kernel(const float* __restrict__ x, const float* __restrict__ W,
                                const float* __restrict__ bias, const float* __restrict__ gumbel,
                                const int* __restrict__ flags, float* __restrict__ out) {
  const size_t idx = (size_t)blockIdx.x * blockDim.x + threadIdx.x;
  const int row = (int)(idx / N_DIM);
  const int col = (int)(idx % N_DIM);
  float o = bias[col];
  const float* xr = x + (size_t)row * D_DIM;
  for (int k = 0; k < D_DIM; ++k) o += xr[k] * W[(size_t)k * N_DIM + col];
  out[idx] = o;
  float v;
  if (flags[col >> 4] == 0) {
    const float oc = fminf(fmaxf(o, -15.f), 15.f);
    const float e2 = __expf(2.f * oc);
    v = (e2 - 1.f) / (e2 + 1.f);
  } else {
    const float t = (o + gumbel[idx]) * TAU_INV;
    float mx = t;
    mx = fmaxf(mx, __shfl_xor(mx, 1));
    mx = fmaxf(mx, __shfl_xor(mx, 2));
    mx = fmaxf(mx, __shfl_xor(mx, 4));
    mx = fmaxf(mx, __shfl_xor(mx, 8));
    float e = __expf(t - mx);
    float ssum = e;
    ssum += __shfl_xor(ssum, 1);
    ssum += __shfl_xor(ssum, 2);
    ssum += __shfl_xor(ssum, 4);
    ssum += __shfl_xor(ssum, 8);
    v = e / ssum;
  }
  out[(size_t)B_DIM * N_DIM + idx] = v;
}

// ---------------------------------------------------------------------------
extern "C" void kernel_launch(void* const* d_in, const int* in_sizes, int n_in,
                              void* d_out, int out_size, void* d_ws, size_t ws_size,
                              hipStream_t stream) {
  const float* x      = (const float*)d_in[0];
  const float* W      = (const float*)d_in[1];
  const float* bias   = (const float*)d_in[2];
  const float* gumbel = (const float*)d_in[3];
  const int*   flags  = (const int*)d_in[4];
  float* out = (float*)d_out;

  const size_t xcnt = (size_t)B_DIM * D_DIM;   // 8,388,608
  const size_t wcnt = (size_t)N_DIM * D_DIM;   // 4,194,304
  const size_t need = (2 * xcnt + wcnt) * sizeof(__bf16);  // ~42 MB

  if (ws_size < need) {
    const long long nblocks = (long long)B_DIM * N_DIM / 256;  // 131072
    fallback_kernel<<<(int)nblocks, 256, 0, stream>>>(x, W, bias, gumbel, flags, out);
    return;
  }

  __bf16* xh  = (__bf16*)d_ws;
  __bf16* xl  = xh + xcnt;
  __bf16* wht = xl + xcnt;

  prep_x<<<xcnt / 4 / 256, 256, 0, stream>>>(x, xh, xl);
  prep_w<<<(N_DIM / 32) * (D_DIM / 32), 256, 0, stream>>>(W, wht);
  gemm_fused<<<(B_DIM / BM) * (N_DIM / BN), THREADS, 0, stream>>>(
      xh, xl, wht, bias, gumbel, flags, out);
}